// Round 3
// baseline (422.312 us; speedup 1.0000x reference)
//
#include <hip/hip_runtime.h>

// Problem constants (match reference setup_inputs)
#define NSAMP 65536
#define DDIM  128
#define SPT   4      // samples per half-wave (software-pipelined)

// Half-wave (32 lanes) per sample-group; lane l owns elements {4l..4l+3} as
// float4, so each row gather is one 512 B transaction per half-wave.
// Projection is linear in x => project (h + r - t) once per score.
// 4 samples per half-wave, double-buffered: sample k+1's 7 row loads are in
// flight while sample k runs its two 5-step shuffle-reduction chains.
__global__ __launch_bounds__(256) void transh_kernel(
    const int* __restrict__ pos_h, const int* __restrict__ pos_t, const int* __restrict__ pos_r,
    const int* __restrict__ neg_h, const int* __restrict__ neg_t, const int* __restrict__ neg_r,
    const float* __restrict__ ent, const float* __restrict__ vvrel, const float* __restrict__ bases,
    float* __restrict__ out)
{
    const int tid  = blockIdx.x * blockDim.x + threadIdx.x;
    const int hw   = tid >> 5;            // half-wave id: 16384 total
    const int sub  = threadIdx.x & 31;
    const int base = hw * SPT;

    // Preload all indices so row-load addresses have no outstanding dependency
    int iph[SPT], ipt[SPT], ipr[SPT], inh[SPT], itn[SPT], inr[SPT];
    #pragma unroll
    for (int k = 0; k < SPT; ++k) {
        const int s = base + k;
        iph[k] = pos_h[s];  ipt[k] = pos_t[s];  ipr[k] = pos_r[s];
        inh[k] = neg_h[s];  itn[k] = neg_t[s];  inr[k] = neg_r[s];
    }

    float4 V[2], A[2], B[2], C[2], NA[2], NB[2], NC[2];

    // prologue: issue sample 0's loads
    {
        V[0]  = ((const float4*)(bases + (size_t)ipr[0] * DDIM))[sub];
        A[0]  = ((const float4*)(ent   + (size_t)iph[0] * DDIM))[sub];
        C[0]  = ((const float4*)(ent   + (size_t)ipt[0] * DDIM))[sub];
        B[0]  = ((const float4*)(vvrel + (size_t)ipr[0] * DDIM))[sub];
        NA[0] = ((const float4*)(ent   + (size_t)inh[0] * DDIM))[sub];
        NC[0] = ((const float4*)(ent   + (size_t)itn[0] * DDIM))[sub];
        NB[0] = ((const float4*)(vvrel + (size_t)inr[0] * DDIM))[sub];
    }

    #pragma unroll
    for (int k = 0; k < SPT; ++k) {
        const int cur = k & 1;
        const int nxt = cur ^ 1;
        if (k + 1 < SPT) {  // issue next sample's loads before computing current
            V[nxt]  = ((const float4*)(bases + (size_t)ipr[k+1] * DDIM))[sub];
            A[nxt]  = ((const float4*)(ent   + (size_t)iph[k+1] * DDIM))[sub];
            C[nxt]  = ((const float4*)(ent   + (size_t)ipt[k+1] * DDIM))[sub];
            B[nxt]  = ((const float4*)(vvrel + (size_t)ipr[k+1] * DDIM))[sub];
            NA[nxt] = ((const float4*)(ent   + (size_t)inh[k+1] * DDIM))[sub];
            NC[nxt] = ((const float4*)(ent   + (size_t)itn[k+1] * DDIM))[sub];
            NB[nxt] = ((const float4*)(vvrel + (size_t)inr[k+1] * DDIM))[sub];
        }

        const float4 v  = V[cur];
        const float4 a  = A[cur],  c  = C[cur],  b  = B[cur];
        const float4 na = NA[cur], nc = NC[cur], nb = NB[cur];

        float4 sp, sn;
        sp.x = a.x + b.x - c.x;   sp.y = a.y + b.y - c.y;
        sp.z = a.z + b.z - c.z;   sp.w = a.w + b.w - c.w;
        sn.x = na.x + nb.x - nc.x; sn.y = na.y + nb.y - nc.y;
        sn.z = na.z + nb.z - nc.z; sn.w = na.w + nb.w - nc.w;

        float vv  = v.x * v.x  + v.y * v.y  + v.z * v.z  + v.w * v.w;
        float vsp = v.x * sp.x + v.y * sp.y + v.z * sp.z + v.w * sp.w;
        float vsn = v.x * sn.x + v.y * sn.y + v.z * sn.z + v.w * sn.w;

        #pragma unroll
        for (int off = 16; off > 0; off >>= 1) {
            vv  += __shfl_xor(vv,  off, 64);
            vsp += __shfl_xor(vsp, off, 64);
            vsn += __shfl_xor(vsn, off, 64);
        }

        const float cp = vsp / vv;
        const float cn = vsn / vv;

        float ap = fabsf(sp.x - cp * v.x) + fabsf(sp.y - cp * v.y)
                 + fabsf(sp.z - cp * v.z) + fabsf(sp.w - cp * v.w);
        float an = fabsf(sn.x - cn * v.x) + fabsf(sn.y - cn * v.y)
                 + fabsf(sn.z - cn * v.z) + fabsf(sn.w - cn * v.w);

        #pragma unroll
        for (int off = 16; off > 0; off >>= 1) {
            ap += __shfl_xor(ap, off, 64);
            an += __shfl_xor(an, off, 64);
        }

        if (sub == 0) {
            const int s = base + k;
            out[s]         = ap;  // pos score
            out[NSAMP + s] = an;  // neg score
        }
    }
}

extern "C" void kernel_launch(void* const* d_in, const int* in_sizes, int n_in,
                              void* d_out, int out_size, void* d_ws, size_t ws_size,
                              hipStream_t stream) {
    const int*   pos_h = (const int*)d_in[0];
    const int*   pos_t = (const int*)d_in[1];
    const int*   pos_r = (const int*)d_in[2];
    const int*   neg_h = (const int*)d_in[3];
    const int*   neg_t = (const int*)d_in[4];
    const int*   neg_r = (const int*)d_in[5];
    const float* ent   = (const float*)d_in[6];
    const float* vvrel = (const float*)d_in[7];
    const float* bases = (const float*)d_in[8];
    float* out = (float*)d_out;

    // Half-wave per SPT samples: 16384 half-waves -> 524288 threads
    const int threads = 256;
    const int blocks  = (NSAMP / SPT) * 32 / threads;  // 2048
    transh_kernel<<<blocks, threads, 0, stream>>>(
        pos_h, pos_t, pos_r, neg_h, neg_t, neg_r, ent, vvrel, bases, out);
}